// Round 1
// baseline (42.251 us; speedup 1.0000x reference)
//
#include <hip/hip_runtime.h>

// ---- problem constants (fixed by reference) ----
#define ROWN   32768
#define NSTEP  25
#define NIN    36
#define NHID   5
#define NOUT   3
#define TTOT   (NSTEP * ROWN)      // 819200 total LIF steps
#define OUTHALF (TTOT * NOUT)      // 2457600 floats per tuple element

// ---- speculation / parallelization parameters ----
#define CHL    128                 // chunk length (steps); boundaries at k*128 are a
                                   // subset of the bitwise-verified k*64 boundaries
#define WARM   384                 // warmup steps (bitwise-verified prior rounds)
#define NCH    (TTOT / CHL)        // 6400 chunks
#define GPW    8                   // chunks per wave (8 lanes per chunk)
#define WPB    4                   // waves per block (256-thread blocks, 8x fewer WGs)
#define MLAG   8                   // m2 pipeline lag == d2 LDS prefetch depth
#define DLAG   16                  // dot global prefetch depth (~380cy coverage)
#define NBLK   (NCH / GPW / WPB)   // 200 blocks of 256 threads
#define EXT    640                 // duplicated rows appended to dot table
                                   // max overrun row: 32767 + 16 + 65*8 - 1 = 33302 < 33408

// ---- ws layout (float offsets) ----
#define DOTROWS (ROWN + EXT)
#define WS_DOT  0                  // [DOTROWS][8] padded dot products (~1.02 MB)
#define WS_SPEC (DOTROWS * 8)      // [NCH][8] speculative post-warmup states
#define WS_END  (WS_SPEC + NCH*8)  // [NCH][8] chunk end states
#define WS_FLAG (WS_END + NCH*8)   // int flag

// Precompute dot1[r][h] = sum_j w1[h][j]*data[r][j], exact sequential-j order,
// contract off (matches reference fp trajectory bitwise). Rows 0..EXT-1 are
// duplicated at ROWN+r so the scan loop needs no wrap mask.
__global__ void snn_dots(const float* __restrict__ data,
                         const float* __restrict__ w1,
                         float* __restrict__ ws) {
#pragma clang fp contract(off)
    int r = blockIdx.x * blockDim.x + threadIdx.x;
    if (r == 0) ((int*)ws)[WS_FLAG] = 0;
    if (r >= ROWN) return;
    const float4* x4 = reinterpret_cast<const float4*>(data + r * NIN);
    float4 xv[9];
#pragma unroll
    for (int q = 0; q < 9; ++q) xv[q] = x4[q];
    const float* xs = reinterpret_cast<const float*>(xv);
    float acc[NHID] = {0.f, 0.f, 0.f, 0.f, 0.f};
#pragma unroll
    for (int j = 0; j < NIN; ++j) {
        float x = xs[j];
#pragma unroll
        for (int h = 0; h < NHID; ++h) {
            float p = w1[h * NIN + j] * x;
            acc[h] = acc[h] + p;
        }
    }
    float* d = ws + WS_DOT + r * 8;
#pragma unroll
    for (int h = 0; h < NHID; ++h) d[h] = acc[h];
    d[5] = 0.f; d[6] = 0.f; d[7] = 0.f;
    if (r < EXT) {
        float* d2 = ws + WS_DOT + (ROWN + r) * 8;
#pragma unroll
        for (int h = 0; h < NHID; ++h) d2[h] = acc[h];
        d2[5] = 0.f; d2[6] = 0.f; d2[7] = 0.f;
    }
}

// ---- 8-lane-per-chunk speculative scan ----
// lane = g*8 + h.  h<5: m1 comp h (input = dot[t][h], global, 16-deep prefetch).
//                  h>=5: m2 comp h-5 (input = LUT d2, MLAG steps behind m1).
// Unified step: m = (0.9*m + inp) + bias; spike iff m>1; m -= spike.
// Selects happen at CONSUME time (16/8 steps after load issue) so waitcnts
// never sit on freshly-issued loads.
template<bool GUARD>
__device__ __forceinline__ void run_chunks(
    const char* __restrict__ dotb,      // byte base of dot table
    const char* __restrict__ lutrow,    // this lane's LUT row base (LDS)
    float bias, int c, int h, bool isM2, int gsh,
    char* __restrict__ outb, char* __restrict__ out2b,
    float* __restrict__ spec, float* __restrict__ endst)
{
#pragma clang fp contract(off)
    const int ts = c * CHL;
    const int t0 = ts - WARM;                     // <0 only in GUARD block
    float m = 0.0f;
    float dvbuf[DLAG], d2buf[MLAG], sbuf[8];
    const int dco = (isM2 ? 4 : h) << 2;          // dot col byte off (m2: dummy, coalesced)
    unsigned offb = ((unsigned)(t0 & (ROWN - 1)) << 5) + (unsigned)dco;
#pragma unroll
    for (int k = 0; k < DLAG; ++k)                // prime the 16-deep dot pipeline
        dvbuf[k] = *(const float*)(dotb + offb + k * 32);
    offb += DLAG * 32;
#pragma unroll
    for (int k = 0; k < MLAG; ++k) d2buf[k] = 0.0f;
    int tg = t0 - (isM2 ? MLAG : 0);              // logical clock (GUARD only)
    unsigned obb = (unsigned)ts * 12u + (unsigned)((isM2 ? (h - NHID) : 0) << 2);

// One 8-step block. HALF selects the dvbuf half (16-step rotation).
#define BLK8(HALF, STORE)                                                    \
  {                                                                          \
    _Pragma("unroll")                                                        \
    for (int k = 0; k < 8; ++k) {                                            \
        float inp = isM2 ? d2buf[k] : dvbuf[(HALF) + k];                     \
        float u = 0.9f * m;                                                  \
        u = u + inp;                                                         \
        u = u + bias;                                                        \
        bool sp = u > 1.0f;                                                  \
        unsigned long long bal = __ballot(sp);                               \
        float um1 = u - 1.0f;                                                \
        m = sp ? um1 : u;                                                    \
        if (GUARD) { if (tg < 0) m = 0.0f; ++tg; }                           \
        dvbuf[(HALF) + k] = *(const float*)(dotb + offb + k * 32);           \
        unsigned a = (unsigned)((bal << 2) >> gsh) & 124u;                   \
        d2buf[k] = *(const float*)(lutrow + a);                              \
        if (STORE) sbuf[k] = sp ? 1.0f : 0.0f;                               \
    }                                                                        \
    offb += 256u;                                                            \
    if (STORE) {                                                             \
        if (isM2) {                                                          \
            _Pragma("unroll")                                                \
            for (int k = 0; k < 8; ++k) {                                    \
                *(float*)(outb  + obb + k * 12) = sbuf[k];                   \
                *(float*)(out2b + obb + k * 12) = sbuf[k];                   \
            }                                                                \
        }                                                                    \
        obb += 96u;                                                          \
    }                                                                        \
  }

    // warmup: 48 blocks = 384 steps (halves alternate 0,8)
    for (int n = 0; n < 24; ++n) { BLK8(0, false) BLK8(8, false) }
    if (!isM2) spec[c * 8 + h] = m;      // m1 state at t = ts
    BLK8(0, false)                        // m2 finishes warmup
    if (isM2) spec[c * 8 + h] = m;       // m2 state at t = ts
    // store region: 16 blocks = 128 m2-steps (halves 8,0 x8, alternation continues)
    for (int n = 0; n < 7; ++n) { BLK8(8, true) BLK8(0, true) }
    BLK8(8, true)
    if (!isM2) endst[c * 8 + h] = m;     // m1 state at t = ts+CHL
    BLK8(0, true)
    if (isM2) endst[c * 8 + h] = m;      // m2 state at t = ts+CHL
#undef BLK8
}

__global__ void __launch_bounds__(256)
snn_chunks(const float* __restrict__ ws,
           const float* __restrict__ b1g, const float* __restrict__ w2g,
           const float* __restrict__ b2g,
           float* __restrict__ out, float* __restrict__ spec,
           float* __restrict__ endst) {
    __shared__ float lutT[3 * 32];       // transposed LUT: lutT[o][mask], 4B stride
    int tid = threadIdx.x;
    if (tid < 32) {                      // exact: lutT[o*32+mask] = w2[o]@bits(mask)
#pragma clang fp contract(off)
        float b0 = (float)(tid & 1), b1v = (float)((tid >> 1) & 1),
              b2v = (float)((tid >> 2) & 1), b3v = (float)((tid >> 3) & 1),
              b4v = (float)((tid >> 4) & 1);
#pragma unroll
        for (int o = 0; o < NOUT; ++o) {
            float d = w2g[o * NHID + 0] * b0;
            d = d + w2g[o * NHID + 1] * b1v;
            d = d + w2g[o * NHID + 2] * b2v;
            d = d + w2g[o * NHID + 3] * b3v;
            d = d + w2g[o * NHID + 4] * b4v;
            lutT[o * 32 + tid] = d;
        }
    }
    __syncthreads();
    int lane = tid & 63;
    int wid  = tid >> 6;
    int gwid = blockIdx.x * WPB + wid;             // global wave id, 0..799
    int g = lane >> 3, h = lane & 7;
    bool isM2 = (h >= NHID);
    float bias = isM2 ? b2g[h - NHID] : b1g[h];
    int c = gwid * GPW + g;
    int gsh = g << 3;                              // ballot >> (group*8)
    const char* lutrow = (const char*)lutT + (isM2 ? ((h - NHID) << 7) : 0);
    const char* dotb = (const char*)(ws + WS_DOT);
    char* outb  = (char*)out;
    char* out2b = (char*)(out + OUTHALF);
    // only chunks with ts < WARM (c*128 < 384 -> c <= 2, all in wave 0) need GUARD
    if (gwid == 0)
        run_chunks<true >(dotb, lutrow, bias, c, h, isM2, gsh, outb, out2b, spec, endst);
    else
        run_chunks<false>(dotb, lutrow, bias, c, h, isM2, gsh, outb, out2b, spec, endst);
}

// ---- exact scalar step (fallback path only) ----
template<bool STORE>
__device__ __forceinline__ void lif_step(int t, const float* __restrict__ dot,
                                         float m1[NHID], float m2[NOUT],
                                         const float B1[NHID],
                                         const float W2[NOUT][NHID],
                                         const float B2[NOUT],
                                         float* __restrict__ out) {
#pragma clang fp contract(off)
    int r = t & (ROWN - 1);
    const float4 lo = *reinterpret_cast<const float4*>(dot + r * 8);
    const float d4 = dot[r * 8 + 4];
    float dv[NHID] = { lo.x, lo.y, lo.z, lo.w, d4 };
    float s1f[NHID];
#pragma unroll
    for (int h = 0; h < NHID; ++h) {
        float u = 0.9f * m1[h];
        u = u + dv[h];
        u = u + B1[h];
        float s = (u > 1.0f) ? 1.0f : 0.0f;
        m1[h] = u - s;
        s1f[h] = s;
    }
#pragma unroll
    for (int o = 0; o < NOUT; ++o) {
        float d2 = W2[o][0] * s1f[0];
        d2 = d2 + W2[o][1] * s1f[1];
        d2 = d2 + W2[o][2] * s1f[2];
        d2 = d2 + W2[o][3] * s1f[3];
        d2 = d2 + W2[o][4] * s1f[4];
        float u = 0.9f * m2[o];
        u = u + d2;
        u = u + B2[o];
        float s = (u > 1.0f) ? 1.0f : 0.0f;
        m2[o] = u - s;
        if (STORE) {
            out[t * NOUT + o] = s;
            out[OUTHALF + t * NOUT + o] = s;
        }
    }
}

// Chain verification: chunk c's post-warmup state must equal chunk c-1's end
// state bitwise. All-equal + exact chunk 0 => outputs exact by induction.
__global__ void snn_check(const float* __restrict__ spec,
                          const float* __restrict__ endst,
                          int* __restrict__ flag) {
    int c = blockIdx.x * blockDim.x + threadIdx.x;
    if (c < 1 || c >= NCH) return;
    bool bad = false;
#pragma unroll
    for (int i = 0; i < 8; ++i)
        bad = bad || (spec[c * 8 + i] != endst[(c - 1) * 8 + i]);
    if (bad) atomicOr(flag, 1);
}

// Exact sequential fallback (runs only if speculation failed anywhere).
__global__ void snn_fallback(const float* __restrict__ ws_dot,
                             const float* __restrict__ b1g,
                             const float* __restrict__ w2g,
                             const float* __restrict__ b2g,
                             float* __restrict__ out,
                             const int* __restrict__ flag) {
    if (*flag == 0) return;
    float B1[NHID], W2[NOUT][NHID], B2[NOUT];
#pragma unroll
    for (int h = 0; h < NHID; ++h) B1[h] = b1g[h];
#pragma unroll
    for (int o = 0; o < NOUT; ++o) {
        B2[o] = b2g[o];
#pragma unroll
        for (int h = 0; h < NHID; ++h) W2[o][h] = w2g[o * NHID + h];
    }
    float m1[NHID] = {0,0,0,0,0};
    float m2[NOUT] = {0,0,0};
    for (int t = 0; t < TTOT; ++t)
        lif_step<true>(t, ws_dot, m1, m2, B1, W2, B2, out);
}

extern "C" void kernel_launch(void* const* d_in, const int* in_sizes, int n_in,
                              void* d_out, int out_size, void* d_ws, size_t ws_size,
                              hipStream_t stream) {
    const float* data = (const float*)d_in[0];
    const float* w1   = (const float*)d_in[1];
    const float* b1   = (const float*)d_in[2];
    const float* w2   = (const float*)d_in[3];
    const float* b2   = (const float*)d_in[4];
    float* out = (float*)d_out;
    float* ws  = (float*)d_ws;
    float* spec  = ws + WS_SPEC;
    float* endst = ws + WS_END;
    int*   flag  = (int*)(ws + WS_FLAG);

    hipLaunchKernelGGL(snn_dots,   dim3(ROWN / 256), dim3(256), 0, stream, data, w1, ws);
    hipLaunchKernelGGL(snn_chunks, dim3(NBLK),       dim3(256), 0, stream,
                       ws, b1, w2, b2, out, spec, endst);
    hipLaunchKernelGGL(snn_check,  dim3((NCH + 255) / 256), dim3(256), 0, stream,
                       spec, endst, flag);
    hipLaunchKernelGGL(snn_fallback, dim3(1), dim3(1), 0, stream,
                       ws, b1, w2, b2, out, flag);
}